// Round 6
// baseline (400.486 us; speedup 1.0000x reference)
//
#include <hip/hip_runtime.h>

#define N_NODES 50000
#define N_EDGES 800000
#define D 64
#define CAP 64

typedef float vf4 __attribute__((ext_vector_type(4)));

// ---------------- KA: score only (pure stream+gather+reduce) ----------------
// 16 lanes per edge, 16 edges per block (R4's proven shape). No atomics, no
// scatter: waves retire at stream speed. e read coalesced+sequential and
// nontemporal (204.8MB, stream-once); h_src row gather (256B rows, random,
// L2/L3-resident). 4-FMA dot + 4-step shfl_xor reduce + expf; lane 0 writes
// w[i] into a SEQUENTIAL 3.2MB array (lanes 0/16/32/48 of a wave hit 16
// contiguous bytes). The R4/R5 lesson: putting the far-atomic + scatter in
// the same wave as the stream stretches wave lifetime ~2x and throttles the
// stream (103-119us fused vs ~80us split-sum predicted).
__global__ __launch_bounds__(256) void ka_score(
    const vf4* __restrict__ h_src4, const vf4* __restrict__ e4,
    const int* __restrict__ src, float* __restrict__ wv) {
    int t = threadIdx.x;
    int i = blockIdx.x * 16 + (t >> 4);        // 800000/16 = 50000 blocks exact
    int l16 = t & 15;
    int s = src[i];                            // broadcast within group
    vf4 ev = __builtin_nontemporal_load(&e4[(size_t)i * 16 + l16]);
    vf4 u  = h_src4[(size_t)s * 16 + l16];
    float p = u[0]*ev[0] + u[1]*ev[1] + u[2]*ev[2] + u[3]*ev[3];
    p += __shfl_xor(p, 1, 16);
    p += __shfl_xor(p, 2, 16);
    p += __shfl_xor(p, 4, 16);
    p += __shfl_xor(p, 8, 16);
    if (l16 == 0)
        wv[i] = __expf(p);
}

// ---------------- KB: bucket build only ----------------
// 1 thread per edge (R0's proven structure + one coalesced w load). Tiny
// wave lifetime -> 12.5K waves give the atomic/scatter path all the
// parallelism it can use, decoupled from the stream kernel.
__global__ __launch_bounds__(256) void kb_bucket(
    const int* __restrict__ src, const int* __restrict__ dst,
    const float* __restrict__ wv,
    int* __restrict__ count, int2* __restrict__ slots) {
    int i = blockIdx.x * 256 + threadIdx.x;    // 800000/256 = 3125 exact
    int s = src[i];
    int d = dst[i];
    float w = wv[i];
    int pos = atomicAdd(&count[d], 1);
    if (pos < CAP)
        slots[(size_t)d * CAP + pos] = make_int2(s, __float_as_int(w));
}

// ---------------- K23: fused aggregate + linear (unchanged) ----------------
// 16 lanes per node, 16 nodes per block (3125 blocks). Aggregation result
// goes straight into the ht LDS tile the linear epilogue consumes.
// Wl padded to stride 65: bank = (65k+o)%32 = (k+o)%32 -> conflict-free for
// both the transpose fill (lanes vary k) and the epilogue read (lanes vary o).
__global__ __launch_bounds__(256) void k23_agg_linear(
    const vf4* __restrict__ h_src4, const vf4* __restrict__ h_dst4,
    const int* __restrict__ count, const int2* __restrict__ slots,
    const float* __restrict__ W, const float* __restrict__ b,
    float* __restrict__ out) {
    __shared__ float Wl[128 * 65];                 // transposed: Wl[k*65+o]
    __shared__ __align__(16) float ht[16][132];
    int t = threadIdx.x;
    for (int i = t; i < 128 * 64; i += 256) {
        int o = i >> 7, k = i & 127;               // W is [64][128] row-major
        Wl[k * 65 + o] = W[i];
    }
    int node0 = blockIdx.x * 16;
    int n = t >> 4;
    int l16 = t & 15;
    int node = node0 + n;
    // h_dst half of ht: independent of aggregation, issue early
    *(vf4*)&ht[n][l16 * 4] = h_dst4[(size_t)node * 16 + l16];

    // ---- aggregation ----
    int cnt = count[node];
    cnt = cnt < CAP ? cnt : CAP;
    const int2* row = slots + (size_t)node * CAP;
    vf4 acc = {0.f, 0.f, 0.f, 0.f};
    float dsum = 0.f;
    int2 se = make_int2(0, 0);                     // batch-0 slot prefetch
    if (l16 < cnt) se = row[l16];
    for (int base = 0; base < cnt; base += 16) {
        int2 cur = se;
        int nxt = base + 16;
        se = make_int2(0, 0);
        if (nxt + l16 < cnt) se = row[nxt + l16];  // prefetch next batch
        // phase 1: issue all 16 gathers
        vf4 us[16];
        #pragma unroll
        for (int j = 0; j < 16; ++j) {
            int sj = __shfl(cur.x, j, 16);
            us[j] = h_src4[(size_t)sj * 16 + l16];
        }
        // phase 2: broadcast w + accumulate
        #pragma unroll
        for (int j = 0; j < 16; ++j) {
            float wj = __int_as_float(__shfl(cur.y, j, 16));
            acc += wj * us[j];
            dsum += wj;                            // same value in all 16 lanes
        }
    }
    float inv = (cnt > 0) ? 1.f / dsum : 0.f;
    acc *= inv;
    *(vf4*)&ht[n][64 + l16 * 4] = acc;
    __syncthreads();

    // ---- linear epilogue: out = [h_dst | h_sum] @ W^T + b ----
    int o = t & 63;
    int g = t >> 6;                                // nodes g*4 .. g*4+3
    float bias = b[o];
    float a0 = bias, a1 = bias, a2 = bias, a3 = bias;
    const float* h0 = &ht[g * 4 + 0][0];
    const float* h1 = &ht[g * 4 + 1][0];
    const float* h2 = &ht[g * 4 + 2][0];
    const float* h3 = &ht[g * 4 + 3][0];
    #pragma unroll
    for (int k = 0; k < 128; k += 4) {
        float w0 = Wl[(k + 0) * 65 + o];
        float w1 = Wl[(k + 1) * 65 + o];
        float w2 = Wl[(k + 2) * 65 + o];
        float w3 = Wl[(k + 3) * 65 + o];
        vf4 p0 = *(const vf4*)&h0[k];
        vf4 p1 = *(const vf4*)&h1[k];
        vf4 p2 = *(const vf4*)&h2[k];
        vf4 p3 = *(const vf4*)&h3[k];
        a0 += p0[0]*w0 + p0[1]*w1 + p0[2]*w2 + p0[3]*w3;
        a1 += p1[0]*w0 + p1[1]*w1 + p1[2]*w2 + p1[3]*w3;
        a2 += p2[0]*w0 + p2[1]*w1 + p2[2]*w2 + p2[3]*w3;
        a3 += p3[0]*w0 + p3[1]*w1 + p3[2]*w2 + p3[3]*w3;
    }
    __builtin_nontemporal_store(a0, &out[(size_t)(node0 + g * 4 + 0) * 64 + o]);
    __builtin_nontemporal_store(a1, &out[(size_t)(node0 + g * 4 + 1) * 64 + o]);
    __builtin_nontemporal_store(a2, &out[(size_t)(node0 + g * 4 + 2) * 64 + o]);
    __builtin_nontemporal_store(a3, &out[(size_t)(node0 + g * 4 + 3) * 64 + o]);
}

extern "C" void kernel_launch(void* const* d_in, const int* in_sizes, int n_in,
                              void* d_out, int out_size, void* d_ws, size_t ws_size,
                              hipStream_t stream) {
    const float* h_src = (const float*)d_in[0];
    const float* h_dst = (const float*)d_in[1];
    const float* e     = (const float*)d_in[2];
    const int*   src   = (const int*)d_in[3];
    const int*   dst   = (const int*)d_in[4];
    const float* W     = (const float*)d_in[5];
    const float* b     = (const float*)d_in[6];
    float* out = (float*)d_out;

    // workspace: count[N] | slots[N*CAP int2] | wv[E f32]
    auto align256 = [](size_t x) { return (x + 255) & ~(size_t)255; };
    char* ws = (char*)d_ws;
    int*  count = (int*)ws;
    int2* slots = (int2*)(ws + align256((size_t)N_NODES * 4));
    float* wv   = (float*)(ws + align256((size_t)N_NODES * 4)
                              + align256((size_t)N_NODES * CAP * 8));

    hipMemsetAsync(count, 0, (size_t)N_NODES * 4, stream);

    ka_score<<<N_EDGES / 16, 256, 0, stream>>>(
        (const vf4*)h_src, (const vf4*)e, src, wv);
    kb_bucket<<<N_EDGES / 256, 256, 0, stream>>>(src, dst, wv, count, slots);
    k23_agg_linear<<<N_NODES / 16, 256, 0, stream>>>(
        (const vf4*)h_src, (const vf4*)h_dst, count, slots, W, b, out);
}

// Round 7
// 376.155 us; speedup vs baseline: 1.0647x; 1.0647x over previous
//
#include <hip/hip_runtime.h>

#define N_NODES 50000
#define N_EDGES 800000
#define D 64
#define CAP 64
#define K1_BLOCKS 3125
#define K1_ITERS 16          // K1_BLOCKS*16 groups * K1_ITERS = 800000 edges

typedef float vf4 __attribute__((ext_vector_type(4)));

// ---------------- K1: fused score + bucket build (persistent, pipelined) ----------------
// R7 structural change vs R4 (which measured best, k1~103us): instead of
// 50000 short-lived blocks (2-load-latency lifetime -> permanent dispatch/
// drain churn, CU residency never fills, stream stuck <3 TB/s), 3125 blocks
// iterate 16 slabs with a 1-deep prefetch pipeline. Per 16-lane group,
// iteration it handles edge i = it*50000 + blockIdx*16 + g: each wave-load
// still covers 1KB contiguous e, and each iteration sweeps one contiguous
// 12.8MB slab -> fully sequential stream. Issue order per iteration:
//   atomic(cur) -> prefetch src/dst/e/h_src(next) -> dot/reduce/exp/store(cur)
// so the far atomic and both gathers always have a full iteration of work
// to hide under, and the slot store's waitcnt (atomic is oldest) does not
// drain the prefetches.
__global__ __launch_bounds__(256) void k1_score_bucket(
    const vf4* __restrict__ h_src4, const vf4* __restrict__ e4,
    const int* __restrict__ src, const int* __restrict__ dst,
    int* __restrict__ count, int2* __restrict__ slots) {
    int t = threadIdx.x;
    int g = t >> 4, l16 = t & 15;
    int g0 = blockIdx.x * 16 + g;              // group id, 0..49999
    // prefetch iteration 0
    int s = src[g0];
    int d = dst[g0];
    vf4 ev = __builtin_nontemporal_load(&e4[(size_t)g0 * 16 + l16]);
    vf4 u  = h_src4[(size_t)s * 16 + l16];
    for (int it = 0; it < K1_ITERS; ++it) {
        int i_cur = it * 50000 + g0;
        int s_cur = s, d_cur = d;
        vf4 ev_c = ev, u_c = u;
        int pos = 0;
        if (l16 == 0)
            pos = atomicAdd(&count[d_cur], 1); // oldest vmem op: in flight now
        if (it < K1_ITERS - 1) {               // prefetch next slab's edge
            int i_n = i_cur + 50000;
            s = src[i_n];
            d = dst[i_n];
            ev = __builtin_nontemporal_load(&e4[(size_t)i_n * 16 + l16]);
            u  = h_src4[(size_t)s * 16 + l16];
        }
        float p = u_c[0]*ev_c[0] + u_c[1]*ev_c[1] + u_c[2]*ev_c[2] + u_c[3]*ev_c[3];
        p += __shfl_xor(p, 1, 16);
        p += __shfl_xor(p, 2, 16);
        p += __shfl_xor(p, 4, 16);
        p += __shfl_xor(p, 8, 16);
        if (l16 == 0) {
            float w = __expf(p);
            if (pos < CAP)
                slots[(size_t)d_cur * CAP + pos] = make_int2(s_cur, __float_as_int(w));
        }
    }
}

// ---------------- K23: fused aggregate + linear (unchanged from R4) ----------------
// 16 lanes per node, 16 nodes per block (3125 blocks). Aggregation result
// goes straight into the ht LDS tile the linear epilogue consumes.
// Wl padded to stride 65: bank = (65k+o)%32 = (k+o)%32 -> conflict-free for
// both the transpose fill (lanes vary k) and the epilogue read (lanes vary o).
__global__ __launch_bounds__(256) void k23_agg_linear(
    const vf4* __restrict__ h_src4, const vf4* __restrict__ h_dst4,
    const int* __restrict__ count, const int2* __restrict__ slots,
    const float* __restrict__ W, const float* __restrict__ b,
    float* __restrict__ out) {
    __shared__ float Wl[128 * 65];                 // transposed: Wl[k*65+o]
    __shared__ __align__(16) float ht[16][132];
    int t = threadIdx.x;
    for (int i = t; i < 128 * 64; i += 256) {
        int o = i >> 7, k = i & 127;               // W is [64][128] row-major
        Wl[k * 65 + o] = W[i];
    }
    int node0 = blockIdx.x * 16;
    int n = t >> 4;
    int l16 = t & 15;
    int node = node0 + n;
    // h_dst half of ht: independent of aggregation, issue early
    *(vf4*)&ht[n][l16 * 4] = h_dst4[(size_t)node * 16 + l16];

    // ---- aggregation ----
    int cnt = count[node];
    cnt = cnt < CAP ? cnt : CAP;
    const int2* row = slots + (size_t)node * CAP;
    vf4 acc = {0.f, 0.f, 0.f, 0.f};
    float dsum = 0.f;
    int2 se = make_int2(0, 0);                     // batch-0 slot prefetch
    if (l16 < cnt) se = row[l16];
    for (int base = 0; base < cnt; base += 16) {
        int2 cur = se;
        int nxt = base + 16;
        se = make_int2(0, 0);
        if (nxt + l16 < cnt) se = row[nxt + l16];  // prefetch next batch
        // phase 1: issue all 16 gathers
        vf4 us[16];
        #pragma unroll
        for (int j = 0; j < 16; ++j) {
            int sj = __shfl(cur.x, j, 16);
            us[j] = h_src4[(size_t)sj * 16 + l16];
        }
        // phase 2: broadcast w + accumulate
        #pragma unroll
        for (int j = 0; j < 16; ++j) {
            float wj = __int_as_float(__shfl(cur.y, j, 16));
            acc += wj * us[j];
            dsum += wj;                            // same value in all 16 lanes
        }
    }
    float inv = (cnt > 0) ? 1.f / dsum : 0.f;
    acc *= inv;
    *(vf4*)&ht[n][64 + l16 * 4] = acc;
    __syncthreads();

    // ---- linear epilogue: out = [h_dst | h_sum] @ W^T + b ----
    int o = t & 63;
    int g = t >> 6;                                // nodes g*4 .. g*4+3
    float bias = b[o];
    float a0 = bias, a1 = bias, a2 = bias, a3 = bias;
    const float* h0 = &ht[g * 4 + 0][0];
    const float* h1 = &ht[g * 4 + 1][0];
    const float* h2 = &ht[g * 4 + 2][0];
    const float* h3 = &ht[g * 4 + 3][0];
    #pragma unroll
    for (int k = 0; k < 128; k += 4) {
        float w0 = Wl[(k + 0) * 65 + o];
        float w1 = Wl[(k + 1) * 65 + o];
        float w2 = Wl[(k + 2) * 65 + o];
        float w3 = Wl[(k + 3) * 65 + o];
        vf4 p0 = *(const vf4*)&h0[k];
        vf4 p1 = *(const vf4*)&h1[k];
        vf4 p2 = *(const vf4*)&h2[k];
        vf4 p3 = *(const vf4*)&h3[k];
        a0 += p0[0]*w0 + p0[1]*w1 + p0[2]*w2 + p0[3]*w3;
        a1 += p1[0]*w0 + p1[1]*w1 + p1[2]*w2 + p1[3]*w3;
        a2 += p2[0]*w0 + p2[1]*w1 + p2[2]*w2 + p2[3]*w3;
        a3 += p3[0]*w0 + p3[1]*w1 + p3[2]*w2 + p3[3]*w3;
    }
    __builtin_nontemporal_store(a0, &out[(size_t)(node0 + g * 4 + 0) * 64 + o]);
    __builtin_nontemporal_store(a1, &out[(size_t)(node0 + g * 4 + 1) * 64 + o]);
    __builtin_nontemporal_store(a2, &out[(size_t)(node0 + g * 4 + 2) * 64 + o]);
    __builtin_nontemporal_store(a3, &out[(size_t)(node0 + g * 4 + 3) * 64 + o]);
}

extern "C" void kernel_launch(void* const* d_in, const int* in_sizes, int n_in,
                              void* d_out, int out_size, void* d_ws, size_t ws_size,
                              hipStream_t stream) {
    const float* h_src = (const float*)d_in[0];
    const float* h_dst = (const float*)d_in[1];
    const float* e     = (const float*)d_in[2];
    const int*   src   = (const int*)d_in[3];
    const int*   dst   = (const int*)d_in[4];
    const float* W     = (const float*)d_in[5];
    const float* b     = (const float*)d_in[6];
    float* out = (float*)d_out;

    // workspace: count[N] | slots[N*CAP int2]
    auto align256 = [](size_t x) { return (x + 255) & ~(size_t)255; };
    char* ws = (char*)d_ws;
    int*  count = (int*)ws;
    int2* slots = (int2*)(ws + align256((size_t)N_NODES * 4));

    hipMemsetAsync(count, 0, (size_t)N_NODES * 4, stream);

    k1_score_bucket<<<K1_BLOCKS, 256, 0, stream>>>(
        (const vf4*)h_src, (const vf4*)e, src, dst, count, slots);
    k23_agg_linear<<<N_NODES / 16, 256, 0, stream>>>(
        (const vf4*)h_src, (const vf4*)h_dst, count, slots, W, b, out);
}